// Round 2
// baseline (254.542 us; speedup 1.0000x reference)
//
#include <hip/hip_runtime.h>
#include <math.h>

// R9: persistent kernel with a SOFTWARE grid barrier (regular launch, graph-
// capturable) — replaces R8's hipLaunchCooperativeKernel, which is illegal
// under stream capture and likely poisoned the capture (container failure).
//  - lam/xn/ring-lam live in registers for all 48 iterations.
//  - center 10x10 per-slot state (p,x,xb,q0,q1,q2) persists in registers
//    across the 12 groups; LDS center stays valid (k=4 also stores xbar).
//    Only ring lines/slots re-staged from global each group.
//  - Two-level sense-reversal barrier (8 leaf counters -> root -> sense),
//    agent-scope atomics + __threadfence for cross-XCD visibility.
//  - Safety: host occupancy check (needs 2 blocks/CU for the exact-capacity
//    512-block grid) + ws_size check; else the proven R7 12-launch fallback.
//    In-kernel spin watchdog turns a residency deadlock into a wrong answer
//    instead of a hung container.
#define XDIM 160
#define YDIM 160
#define TDIM 16
#define NB 2
#define T_ITERS 48
#define TILE 10
#define R1S 16            // level-1 region side (TILE+6)
#define R0S 18            // xbar staging side (TILE+8)
#define TPT (XDIM / TILE) // 16 tiles per side
#define NTHR 512
#define NGRP (T_ITERS / 4)
#define NLEAF 8           // barrier fan-in

constexpr int VOL  = XDIM * YDIM * TDIM;  // 409600
constexpr int NX   = NB * VOL;            // 819200
constexpr int NBLK = NB * TPT * TPT;      // 512 blocks = exactly 2/CU

typedef _Float16 hreal;
typedef _Float16 half4 __attribute__((ext_vector_type(4)));

__device__ __forceinline__ float clampl(float v, float l) {
    return fminf(fmaxf(v, -l), l);
}
__device__ __forceinline__ int wrap(int v) {  // v in [-4, 164)
    return v < 0 ? v + XDIM : (v >= XDIM ? v - XDIM : v);
}
__device__ __forceinline__ void ld4(const float* p, float* d) {
    float4 v = *(const float4*)p;
    d[0] = v.x; d[1] = v.y; d[2] = v.z; d[3] = v.w;
}
__device__ __forceinline__ void st4(float* p, const float* s) {
    *(float4*)p = make_float4(s[0], s[1], s[2], s[3]);
}
__device__ __forceinline__ void h2f4(const hreal* p, float* d) {
    half4 v = *(const half4*)p;
    d[0] = (float)v.x; d[1] = (float)v.y; d[2] = (float)v.z; d[3] = (float)v.w;
}
// DPP quad rotates (t is quad-uniform per line, so exec within a quad is
// all-or-nothing and DPP source lanes are always active).
__device__ __forceinline__ float qrot_up(float x) {  // lane i <- (i&~3)|((i+1)&3)
    return __int_as_float(__builtin_amdgcn_update_dpp(
        0, __float_as_int(x), 0x39, 0xF, 0xF, true));
}
__device__ __forceinline__ float qrot_dn(float x) {  // lane i <- (i&~3)|((i+3)&3)
    return __int_as_float(__builtin_amdgcn_update_dpp(
        0, __float_as_int(x), 0x93, 0xF, 0xF, true));
}

// ---- software grid barrier -------------------------------------------------
// bar layout (uint32): [0..127] 8 leaf counters at 64B stride, [128] root,
// [129] sense (monotonic). Zeroed by init_kernel each run.
__device__ __forceinline__ void grid_barrier(unsigned* bar) {
    __threadfence();                       // release my block's global writes
    __syncthreads();
    if (threadIdx.x == 0) {
        unsigned s = __hip_atomic_load(bar + 129, __ATOMIC_RELAXED,
                                       __HIP_MEMORY_SCOPE_AGENT);
        const unsigned leaf = (blockIdx.x & (NLEAF - 1)) * 16;
        const unsigned per  = NBLK / NLEAF;   // 64 blocks per leaf
        bool done = false;
        if (__hip_atomic_fetch_add(bar + leaf, 1u, __ATOMIC_ACQ_REL,
                                   __HIP_MEMORY_SCOPE_AGENT) == per - 1u) {
            __hip_atomic_store(bar + leaf, 0u, __ATOMIC_RELAXED,
                               __HIP_MEMORY_SCOPE_AGENT);
            if (__hip_atomic_fetch_add(bar + 128, 1u, __ATOMIC_ACQ_REL,
                                       __HIP_MEMORY_SCOPE_AGENT) == NLEAF - 1u) {
                __hip_atomic_store(bar + 128, 0u, __ATOMIC_RELAXED,
                                   __HIP_MEMORY_SCOPE_AGENT);
                __hip_atomic_store(bar + 129, s + 1u, __ATOMIC_RELEASE,
                                   __HIP_MEMORY_SCOPE_AGENT);
                done = true;
            }
        }
        if (!done) {
            // watchdog: ~0.5s worth of polls, then bail (wrong answer, not hang)
            for (unsigned it = 0; it < (1u << 22); ++it) {
                if (__hip_atomic_load(bar + 129, __ATOMIC_RELAXED,
                                      __HIP_MEMORY_SCOPE_AGENT) != s) break;
                __builtin_amdgcn_s_sleep(4);
            }
        }
    }
    __syncthreads();
    __threadfence();                       // acquire other blocks' writes
}

__global__ __launch_bounds__(256) void init_kernel(
    const float* __restrict__ x, const float* __restrict__ lam,
    float* __restrict__ pA, float* __restrict__ xA,
    hreal* __restrict__ xbAh, hreal* __restrict__ qAh,
    hreal* __restrict__ lamh, hreal* __restrict__ xnh,
    unsigned* __restrict__ bar)
{
    int i = blockIdx.x * blockDim.x + threadIdx.x;
    if (i < NX) {
        float v = x[i];
        pA[i] = v; xA[i] = v;
        xbAh[i] = (hreal)v;
        xnh[i]  = (hreal)v;
    }
    if (i < 3 * NX) {
        qAh[i]  = (hreal)0.f;
        lamh[i] = (hreal)lam[i];
    }
    if (bar && i < 130) bar[i] = 0u;       // reset barrier state each replay
}

// ---------------------------------------------------------------------------
// R9 persistent kernel
// ---------------------------------------------------------------------------
__global__ __launch_bounds__(NTHR, 4) void pd_persist(
    const hreal* __restrict__ xnh, const hreal* __restrict__ lamh,
    float* __restrict__ pA, float* __restrict__ pB,
    float* __restrict__ xA, float* __restrict__ xB,
    hreal* __restrict__ xbA, hreal* __restrict__ xbB,
    hreal* __restrict__ qA, hreal* __restrict__ qB,
    unsigned* __restrict__ bar,
    float sigma, float inv1ps, float tau, float theta)
{
    __shared__ float xbS[R0S * R0S * TDIM];        // 20.25 KB
    __shared__ float q0S[(R1S + 1) * R1S * TDIM];  // 17 KB
    __shared__ float q1S[R1S * (R1S + 1) * TDIM];  // 17 KB  -> 54.25 KB

    const int tid = threadIdx.x;
    const int b   = blockIdx.x / (TPT * TPT);
    const int rem = blockIdx.x % (TPT * TPT);
    const int X0  = (rem / TPT) * TILE;
    const int Y0  = (rem % TPT) * TILE;
    const int xbase = b * VOL, qbase = b * 3 * VOL;
    const int t0 = (tid & 3) * 4;

    // persistent per-slot state (2 slots/thread)
    float p[2][4], xv[2][4], xb[2][4], q0[2][4], q1[2][4], q2[2][4];
    half4 XNr[2], L0r[2], L1r[2], L2r[2];

    // constants: loaded exactly once for the whole 48 iterations
    #pragma unroll
    for (int m = 0; m < 2; ++m) {
        int line = 128 * m + (tid >> 2);
        int lx = line >> 4, ly = line & 15;
        int gx = wrap(X0 - 3 + lx), gy = wrap(Y0 - 3 + ly);
        int off  = xbase + (gx * YDIM + gy) * TDIM + t0;
        int qoff = qbase + (gx * YDIM + gy) * TDIM + t0;
        XNr[m] = *(const half4*)(xnh + off);
        L0r[m] = *(const half4*)(lamh + qoff);
        L1r[m] = *(const half4*)(lamh + qoff + VOL);
        L2r[m] = *(const half4*)(lamh + qoff + 2 * VOL);
    }
    half4 LRr;
    if (tid < 64) {
        int rly = tid >> 2;
        LRr = *(const half4*)(lamh + qbase +
              (wrap(X0 - 4) * YDIM + wrap(Y0 - 3 + rly)) * TDIM + t0);
    } else if (tid < 128) {
        int rlx = (tid - 64) >> 2;
        LRr = *(const half4*)(lamh + qbase + VOL +
              (wrap(X0 - 3 + rlx) * YDIM + wrap(Y0 - 4)) * TDIM + t0);
    }

    #pragma unroll 1
    for (int g = 0; g < NGRP; ++g) {
        const bool e = (g & 1) == 0;
        const bool first = (g == 0);
        const float* __restrict__ pIn  = e ? pA : pB;
        float* __restrict__ pOut       = e ? pB : pA;
        const float* __restrict__ xIn  = e ? xA : xB;
        float* __restrict__ xOut       = e ? xB : xA;
        const hreal* __restrict__ xbIn = e ? xbA : xbB;
        hreal* __restrict__ xbOut      = e ? xbB : xbA;
        const hreal* __restrict__ qIn  = e ? qA : qB;
        hreal* __restrict__ qOut       = e ? qB : qA;

        // ---- stage halos: full tile on g==0, ring-only afterwards ----
        // (xbS center [4,14)^2 == k=4 phase C fp32 writes of last group;
        //  q0S preserved box sx[3,14) sy[3,13); q1S sx[3,13) sy[3,14))
        for (int s = tid; s < R0S * R0S * 4; s += NTHR) {
            int sq = s & 3, ln = s >> 2;
            int rx = ln / R0S, ry = ln % R0S;
            if (!first && rx >= 4 && rx < 14 && ry >= 4 && ry < 14) continue;
            int gx = wrap(X0 - 4 + rx), gy = wrap(Y0 - 4 + ry);
            float v[4];
            h2f4(xbIn + xbase + (gx * YDIM + gy) * TDIM + sq * 4, v);
            st4(xbS + ln * TDIM + sq * 4, v);
        }
        for (int s = tid; s < 17 * 16 * 4; s += NTHR) {
            int sq = s & 3, ln = s >> 2;
            int sx = ln / 16, sy = ln % 16;
            if (!first && sx >= 3 && sx < 14 && sy >= 3 && sy < 13) continue;
            int gx = wrap(X0 - 4 + sx), gy = wrap(Y0 - 3 + sy);
            float v[4];
            h2f4(qIn + qbase + (gx * YDIM + gy) * TDIM + sq * 4, v);
            st4(q0S + ln * TDIM + sq * 4, v);
        }
        for (int s = tid; s < 16 * 17 * 4; s += NTHR) {
            int sq = s & 3, ln = s >> 2;
            int sx = ln / 17, sy = ln % 17;
            if (!first && sx >= 3 && sx < 13 && sy >= 3 && sy < 14) continue;
            int gx = wrap(X0 - 3 + sx), gy = wrap(Y0 - 4 + sy);
            float v[4];
            h2f4(qIn + qbase + VOL + (gx * YDIM + gy) * TDIM + sq * 4, v);
            st4(q1S + ln * TDIM + sq * 4, v);
        }

        // ---- per-slot reload: halo slots only (all slots on g==0) ----
        #pragma unroll
        for (int m = 0; m < 2; ++m) {
            int line = 128 * m + (tid >> 2);
            int lx = line >> 4, ly = line & 15;
            bool c = lx >= 3 && lx < 13 && ly >= 3 && ly < 13;
            if (first || !c) {
                int gx = wrap(X0 - 3 + lx), gy = wrap(Y0 - 3 + ly);
                int off  = xbase + (gx * YDIM + gy) * TDIM + t0;
                int qoff = qbase + (gx * YDIM + gy) * TDIM + t0;
                ld4(pIn + off, p[m]);
                ld4(xIn + off, xv[m]);
                h2f4(qIn + qoff + 2 * VOL, q2[m]);
            }
        }
        __syncthreads();
        #pragma unroll
        for (int m = 0; m < 2; ++m) {
            int line = 128 * m + (tid >> 2);
            int lx = line >> 4, ly = line & 15;
            bool c = lx >= 3 && lx < 13 && ly >= 3 && ly < 13;
            if (first || !c)
                ld4(xbS + ((lx + 1) * R0S + (ly + 1)) * TDIM + t0, xb[m]);
        }

        // ---- level loop: k = 1..4 ----
        #pragma unroll
        for (int k = 1; k <= 4; ++k) {
            const int lo = k - 1, hi = 17 - k;

            if (k == 1) {
                // level-1 backward rings (outside R1): q at lx=-1 / ly=-1
                if (tid < 64) {
                    int rly = tid >> 2;
                    float qr[4], xbc[4], xpx[4];
                    ld4(q0S + (0 * R1S + rly) * TDIM + t0, qr);
                    ld4(xbS + (0 * R0S + (rly + 1)) * TDIM + t0, xbc);
                    ld4(xbS + (1 * R0S + (rly + 1)) * TDIM + t0, xpx);
                    #pragma unroll
                    for (int j = 0; j < 4; ++j)
                        qr[j] = clampl(qr[j] + sigma * (xpx[j] - xbc[j]), (float)LRr[j]);
                    st4(q0S + (0 * R1S + rly) * TDIM + t0, qr);
                } else if (tid < 128) {
                    int rlx = (tid - 64) >> 2;
                    float qr[4], xbc[4], xpy[4];
                    ld4(q1S + (rlx * 17 + 0) * TDIM + t0, qr);
                    ld4(xbS + ((rlx + 1) * R0S + 0) * TDIM + t0, xbc);
                    ld4(xbS + ((rlx + 1) * R0S + 1) * TDIM + t0, xpy);
                    #pragma unroll
                    for (int j = 0; j < 4; ++j)
                        qr[j] = clampl(qr[j] + sigma * (xpy[j] - xbc[j]), (float)LRr[j]);
                    st4(q1S + (rlx * 17 + 0) * TDIM + t0, qr);
                }
            }

            // ===== phase B =====
            #pragma unroll
            for (int m = 0; m < 2; ++m) {
                int line = 128 * m + (tid >> 2);
                int lx = line >> 4, ly = line & 15;
                bool inX = (lx >= lo && lx < hi), inY = (ly >= lo && ly < hi);
                bool aq0 = inY && (lx >= lo - 1) && (lx < hi);
                bool aq1 = inX && (ly >= lo - 1) && (ly < hi);
                bool ax  = inX && inY;

                if (k == 1) {   // center slots keep last group's fp32 q0/q1
                    bool c = lx >= 3 && lx < 13 && ly >= 3 && ly < 13;
                    if (first || !c) {
                        ld4(q0S + ((lx + 1) * R1S + ly) * TDIM + t0, q0[m]);
                        ld4(q1S + (lx * 17 + (ly + 1)) * TDIM + t0, q1[m]);
                    }
                }
                if (aq0) {
                    float xpx[4];
                    ld4(xbS + ((lx + 2) * R0S + (ly + 1)) * TDIM + t0, xpx);
                    #pragma unroll
                    for (int j = 0; j < 4; ++j)
                        q0[m][j] = clampl(q0[m][j] + sigma * (xpx[j] - xb[m][j]),
                                          (float)L0r[m][j]);
                    st4(q0S + ((lx + 1) * R1S + ly) * TDIM + t0, q0[m]);
                }
                if (aq1) {
                    float xpy[4];
                    ld4(xbS + ((lx + 1) * R0S + (ly + 2)) * TDIM + t0, xpy);
                    #pragma unroll
                    for (int j = 0; j < 4; ++j)
                        q1[m][j] = clampl(q1[m][j] + sigma * (xpy[j] - xb[m][j]),
                                          (float)L1r[m][j]);
                    st4(q1S + (lx * 17 + (ly + 1)) * TDIM + t0, q1[m]);
                }
                if (ax) {
                    float xb_tp = qrot_up(xb[m][0]);   // xbar at t0+4
                    #pragma unroll
                    for (int j = 0; j < 4; ++j) {
                        float gt = ((j < 3) ? xb[m][j + 1] : xb_tp) - xb[m][j];
                        q2[m][j] = clampl(q2[m][j] + sigma * gt, (float)L2r[m][j]);
                        p[m][j]  = (p[m][j] + sigma * (xb[m][j] - (float)XNr[m][j]))
                                   * inv1ps;
                    }
                }
            }
            __syncthreads();

            // ===== phase C =====
            #pragma unroll
            for (int m = 0; m < 2; ++m) {
                int line = 128 * m + (tid >> 2);
                int lx = line >> 4, ly = line & 15;
                bool ax = (lx >= lo && lx < hi && ly >= lo && ly < hi);
                if (ax) {
                    float q0b[4], q1b[4];
                    ld4(q0S + (lx * R1S + ly) * TDIM + t0, q0b);
                    ld4(q1S + (lx * 17 + ly) * TDIM + t0, q1b);
                    float q2tm = qrot_dn(q2[m][3]);          // new, t0-1
                    #pragma unroll
                    for (int j = 0; j < 4; ++j) {
                        float q2p = (j == 0) ? q2tm : q2[m][j - 1];
                        float div = (q0b[j] - q0[m][j]) + (q1b[j] - q1[m][j])
                                  + (q2p - q2[m][j]);
                        float xnew = xv[m][j] - tau * (p[m][j] + div);
                        xb[m][j] = xnew + theta * (xnew - xv[m][j]);
                        xv[m][j] = xnew;
                    }
                    // k=4 also stores: keeps LDS center valid across groups
                    st4(xbS + ((lx + 1) * R0S + (ly + 1)) * TDIM + t0, xb[m]);
                }
            }
            if (k < 4) __syncthreads();
        }

        // ---- epilogue: center 10x10 lines to global (neighbors' halo) ----
        #pragma unroll
        for (int m = 0; m < 2; ++m) {
            int line = 128 * m + (tid >> 2);
            int lx = line >> 4, ly = line & 15;
            if (lx >= 3 && lx < 13 && ly >= 3 && ly < 13) {
                int gx = X0 + lx - 3, gy = Y0 + ly - 3;
                int off  = xbase + (gx * YDIM + gy) * TDIM + t0;
                int qoff = qbase + (gx * YDIM + gy) * TDIM + t0;
                st4(pOut + off, p[m]);
                st4(xOut + off, xv[m]);
                half4 h;
                h.x = (hreal)xb[m][0]; h.y = (hreal)xb[m][1];
                h.z = (hreal)xb[m][2]; h.w = (hreal)xb[m][3];
                *(half4*)(xbOut + off) = h;
                h.x = (hreal)q0[m][0]; h.y = (hreal)q0[m][1];
                h.z = (hreal)q0[m][2]; h.w = (hreal)q0[m][3];
                *(half4*)(qOut + qoff) = h;
                h.x = (hreal)q1[m][0]; h.y = (hreal)q1[m][1];
                h.z = (hreal)q1[m][2]; h.w = (hreal)q1[m][3];
                *(half4*)(qOut + qoff + VOL) = h;
                h.x = (hreal)q2[m][0]; h.y = (hreal)q2[m][1];
                h.z = (hreal)q2[m][2]; h.w = (hreal)q2[m][3];
                *(half4*)(qOut + qoff + 2 * VOL) = h;
            }
        }

        if (g + 1 < NGRP) grid_barrier(bar);
    }
}

// ---------------------------------------------------------------------------
// Fallback: proven R7 12-launch kernel, unchanged
// ---------------------------------------------------------------------------
__global__ __launch_bounds__(NTHR, 4) void pd_step4(
    const hreal* __restrict__ xnh, const hreal* __restrict__ lamh,
    const float* __restrict__ pIn, float* __restrict__ pOut,
    const float* __restrict__ xIn, float* __restrict__ xOut,
    const hreal* __restrict__ xbIn, hreal* __restrict__ xbOut,
    const hreal* __restrict__ qIn, hreal* __restrict__ qOut,
    float sigma, float inv1ps, float tau, float theta)
{
    __shared__ float xbS[R0S * R0S * TDIM];
    __shared__ float q0S[(R1S + 1) * R1S * TDIM];
    __shared__ float q1S[R1S * (R1S + 1) * TDIM];

    const int tid = threadIdx.x;
    const int b   = blockIdx.x / (TPT * TPT);
    const int rem = blockIdx.x % (TPT * TPT);
    const int X0  = (rem / TPT) * TILE;
    const int Y0  = (rem % TPT) * TILE;
    const int xbase = b * VOL, qbase = b * 3 * VOL;

    const int qd = tid & 3, t0 = qd * 4;
    const int lane  = tid & 63;
    const int upSrc = (lane & 60) | ((lane + 1) & 3);
    const int dnSrc = (lane & 60) | ((lane + 3) & 3);

    for (int s = tid; s < R0S * R0S * 4; s += NTHR) {
        int sq = s & 3, ln = s >> 2;
        int rx = ln / R0S, ry = ln % R0S;
        int gx = wrap(X0 - 4 + rx), gy = wrap(Y0 - 4 + ry);
        float v[4];
        h2f4(xbIn + xbase + (gx * YDIM + gy) * TDIM + sq * 4, v);
        st4(xbS + ln * TDIM + sq * 4, v);
    }
    for (int s = tid; s < 17 * 16 * 4; s += NTHR) {
        int sq = s & 3, ln = s >> 2;
        int sx = ln / 16, sy = ln % 16;
        int gx = wrap(X0 - 4 + sx), gy = wrap(Y0 - 3 + sy);
        float v[4];
        h2f4(qIn + qbase + (gx * YDIM + gy) * TDIM + sq * 4, v);
        st4(q0S + ln * TDIM + sq * 4, v);
    }
    for (int s = tid; s < 16 * 17 * 4; s += NTHR) {
        int sq = s & 3, ln = s >> 2;
        int sx = ln / 17, sy = ln % 17;
        int gx = wrap(X0 - 3 + sx), gy = wrap(Y0 - 4 + sy);
        float v[4];
        h2f4(qIn + qbase + VOL + (gx * YDIM + gy) * TDIM + sq * 4, v);
        st4(q1S + ln * TDIM + sq * 4, v);
    }

    float p[2][4], xv[2][4], xb[2][4], q0[2][4], q1[2][4], q2[2][4];
    half4 XNr[2], L0r[2], L1r[2], L2r[2];
    #pragma unroll
    for (int m = 0; m < 2; ++m) {
        int line = 128 * m + (tid >> 2);
        int lx = line >> 4, ly = line & 15;
        int gx = wrap(X0 - 3 + lx), gy = wrap(Y0 - 3 + ly);
        int off  = xbase + (gx * YDIM + gy) * TDIM + t0;
        int qoff = qbase + (gx * YDIM + gy) * TDIM + t0;
        ld4(pIn + off, p[m]);
        ld4(xIn + off, xv[m]);
        h2f4(qIn + qoff + 2 * VOL, q2[m]);
        XNr[m] = *(const half4*)(xnh + off);
        L0r[m] = *(const half4*)(lamh + qoff);
        L1r[m] = *(const half4*)(lamh + qoff + VOL);
        L2r[m] = *(const half4*)(lamh + qoff + 2 * VOL);
    }

    half4 LRr;
    if (tid < 64) {
        int rly = tid >> 2;
        LRr = *(const half4*)(lamh + qbase +
              (wrap(X0 - 4) * YDIM + wrap(Y0 - 3 + rly)) * TDIM + t0);
    } else if (tid < 128) {
        int rlx = (tid - 64) >> 2;
        LRr = *(const half4*)(lamh + qbase + VOL +
              (wrap(X0 - 3 + rlx) * YDIM + wrap(Y0 - 4)) * TDIM + t0);
    }

    __syncthreads();

    #pragma unroll
    for (int m = 0; m < 2; ++m) {
        int line = 128 * m + (tid >> 2);
        int lx = line >> 4, ly = line & 15;
        ld4(xbS + ((lx + 1) * R0S + (ly + 1)) * TDIM + t0, xb[m]);
    }

    #pragma unroll
    for (int k = 1; k <= 4; ++k) {
        const int lo = k - 1, hi = 17 - k;

        if (k == 1) {
            if (tid < 64) {
                int rly = tid >> 2;
                float qr[4], xbc[4], xpx[4];
                ld4(q0S + (0 * R1S + rly) * TDIM + t0, qr);
                ld4(xbS + (0 * R0S + (rly + 1)) * TDIM + t0, xbc);
                ld4(xbS + (1 * R0S + (rly + 1)) * TDIM + t0, xpx);
                #pragma unroll
                for (int j = 0; j < 4; ++j)
                    qr[j] = clampl(qr[j] + sigma * (xpx[j] - xbc[j]), (float)LRr[j]);
                st4(q0S + (0 * R1S + rly) * TDIM + t0, qr);
            } else if (tid < 128) {
                int rlx = (tid - 64) >> 2;
                float qr[4], xbc[4], xpy[4];
                ld4(q1S + (rlx * 17 + 0) * TDIM + t0, qr);
                ld4(xbS + ((rlx + 1) * R0S + 0) * TDIM + t0, xbc);
                ld4(xbS + ((rlx + 1) * R0S + 1) * TDIM + t0, xpy);
                #pragma unroll
                for (int j = 0; j < 4; ++j)
                    qr[j] = clampl(qr[j] + sigma * (xpy[j] - xbc[j]), (float)LRr[j]);
                st4(q1S + (rlx * 17 + 0) * TDIM + t0, qr);
            }
        }

        #pragma unroll
        for (int m = 0; m < 2; ++m) {
            int line = 128 * m + (tid >> 2);
            int lx = line >> 4, ly = line & 15;
            bool inX = (lx >= lo && lx < hi), inY = (ly >= lo && ly < hi);
            bool aq0 = inY && (lx >= lo - 1) && (lx < hi);
            bool aq1 = inX && (ly >= lo - 1) && (ly < hi);
            bool ax  = inX && inY;

            if (k == 1) {
                ld4(q0S + ((lx + 1) * R1S + ly) * TDIM + t0, q0[m]);
                ld4(q1S + (lx * 17 + (ly + 1)) * TDIM + t0, q1[m]);
            }
            if (aq0) {
                float xpx[4];
                ld4(xbS + ((lx + 2) * R0S + (ly + 1)) * TDIM + t0, xpx);
                #pragma unroll
                for (int j = 0; j < 4; ++j)
                    q0[m][j] = clampl(q0[m][j] + sigma * (xpx[j] - xb[m][j]),
                                      (float)L0r[m][j]);
                st4(q0S + ((lx + 1) * R1S + ly) * TDIM + t0, q0[m]);
            }
            if (aq1) {
                float xpy[4];
                ld4(xbS + ((lx + 1) * R0S + (ly + 2)) * TDIM + t0, xpy);
                #pragma unroll
                for (int j = 0; j < 4; ++j)
                    q1[m][j] = clampl(q1[m][j] + sigma * (xpy[j] - xb[m][j]),
                                      (float)L1r[m][j]);
                st4(q1S + (lx * 17 + (ly + 1)) * TDIM + t0, q1[m]);
            }
            if (ax) {
                float xb_tp = __shfl(xb[m][0], upSrc, 64);
                #pragma unroll
                for (int j = 0; j < 4; ++j) {
                    float gt = ((j < 3) ? xb[m][j + 1] : xb_tp) - xb[m][j];
                    q2[m][j] = clampl(q2[m][j] + sigma * gt, (float)L2r[m][j]);
                    p[m][j]  = (p[m][j] + sigma * (xb[m][j] - (float)XNr[m][j]))
                               * inv1ps;
                }
            }
        }
        __syncthreads();

        #pragma unroll
        for (int m = 0; m < 2; ++m) {
            int line = 128 * m + (tid >> 2);
            int lx = line >> 4, ly = line & 15;
            bool ax = (lx >= lo && lx < hi && ly >= lo && ly < hi);
            if (ax) {
                float q0b[4], q1b[4];
                ld4(q0S + (lx * R1S + ly) * TDIM + t0, q0b);
                ld4(q1S + (lx * 17 + ly) * TDIM + t0, q1b);
                float q2tm = __shfl(q2[m][3], dnSrc, 64);
                #pragma unroll
                for (int j = 0; j < 4; ++j) {
                    float q2p = (j == 0) ? q2tm : q2[m][j - 1];
                    float div = (q0b[j] - q0[m][j]) + (q1b[j] - q1[m][j])
                              + (q2p - q2[m][j]);
                    float xnew = xv[m][j] - tau * (p[m][j] + div);
                    xb[m][j] = xnew + theta * (xnew - xv[m][j]);
                    xv[m][j] = xnew;
                }
                if (k < 4)
                    st4(xbS + ((lx + 1) * R0S + (ly + 1)) * TDIM + t0, xb[m]);
            }
        }
        if (k < 4) __syncthreads();
    }

    #pragma unroll
    for (int m = 0; m < 2; ++m) {
        int line = 128 * m + (tid >> 2);
        int lx = line >> 4, ly = line & 15;
        if (lx >= 3 && lx < 13 && ly >= 3 && ly < 13) {
            int gx = X0 + lx - 3, gy = Y0 + ly - 3;
            int off  = xbase + (gx * YDIM + gy) * TDIM + t0;
            int qoff = qbase + (gx * YDIM + gy) * TDIM + t0;
            st4(pOut + off, p[m]);
            st4(xOut + off, xv[m]);
            half4 h;
            h.x = (hreal)xb[m][0]; h.y = (hreal)xb[m][1];
            h.z = (hreal)xb[m][2]; h.w = (hreal)xb[m][3];
            *(half4*)(xbOut + off) = h;
            h.x = (hreal)q0[m][0]; h.y = (hreal)q0[m][1];
            h.z = (hreal)q0[m][2]; h.w = (hreal)q0[m][3];
            *(half4*)(qOut + qoff) = h;
            h.x = (hreal)q1[m][0]; h.y = (hreal)q1[m][1];
            h.z = (hreal)q1[m][2]; h.w = (hreal)q1[m][3];
            *(half4*)(qOut + qoff + VOL) = h;
            h.x = (hreal)q2[m][0]; h.y = (hreal)q2[m][1];
            h.z = (hreal)q2[m][2]; h.w = (hreal)q2[m][3];
            *(half4*)(qOut + qoff + 2 * VOL) = h;
        }
    }
}

extern "C" void kernel_launch(void* const* d_in, const int* in_sizes, int n_in,
                              void* d_out, int out_size, void* d_ws, size_t ws_size,
                              hipStream_t stream) {
    const float* x   = (const float*)d_in[0];
    const float* lam = (const float*)d_in[1];
    float* out = (float*)d_out;
    float* ws  = (float*)d_ws;

    float* pA  = ws;
    float* pB  = ws + (size_t)NX;
    float* xBb = ws + (size_t)2 * NX;
    float* xAb = out;   // final group (odd parity) writes A family -> d_out
    hreal* hb  = (hreal*)(ws + (size_t)3 * NX);
    hreal* xbAh = hb;
    hreal* xbBh = hb + (size_t)NX;
    hreal* qAh  = hb + (size_t)2 * NX;
    hreal* qBh  = hb + (size_t)5 * NX;
    hreal* lamh = hb + (size_t)8 * NX;
    hreal* xnh  = hb + (size_t)11 * NX;
    unsigned* bar = (unsigned*)(ws + (size_t)9 * NX);   // 130 uints past fp16 region

    const size_t ws_need = (size_t)9 * NX * sizeof(float) + 130 * sizeof(unsigned);

    const double s10 = 1.0 / (1.0 + exp(-10.0));
    const double L   = sqrt(13.0);
    float sigma  = (float)(s10 / L);
    float tau    = sigma;
    float theta  = (float)s10;
    float inv1ps = (float)(1.0 / (1.0 + s10 / L));

    // Decide path once: persistent kernel needs all 512 blocks co-resident
    // (2 blocks/CU x 256 CU) and workspace room for the barrier.
    static int persist_ok = -1;
    if (persist_ok < 0) {
        int nb = 0;
        hipError_t oe = hipOccupancyMaxActiveBlocksPerMultiprocessor(
            &nb, pd_persist, NTHR, 0);
        persist_ok = (oe == hipSuccess && nb >= 2) ? 1 : 0;
        (void)hipGetLastError();
    }
    const bool use_persist = persist_ok == 1 && ws_size >= ws_need;

    init_kernel<<<(3 * NX + 255) / 256, 256, 0, stream>>>(
        x, lam, pA, xAb, xbAh, qAh, lamh, xnh, use_persist ? bar : nullptr);

    if (use_persist) {
        pd_persist<<<NBLK, NTHR, 0, stream>>>(
            xnh, lamh, pA, pB, xAb, xBb, xbAh, xbBh, qAh, qBh, bar,
            sigma, inv1ps, tau, theta);
    } else {
        for (int j = 0; j < NGRP; ++j) {
            const bool e = (j & 1) == 0;
            pd_step4<<<NBLK, NTHR, 0, stream>>>(
                xnh, lamh,
                e ? pA : pB,   e ? pB : pA,
                e ? xAb : xBb, e ? xBb : xAb,
                e ? xbAh : xbBh, e ? xbBh : xbAh,
                e ? qAh : qBh,  e ? qBh : qAh,
                sigma, inv1ps, tau, theta);
        }
    }
}

// Round 3
// 252.370 us; speedup vs baseline: 1.0086x; 1.0086x over previous
//
#include <hip/hip_runtime.h>
#include <math.h>

// R10: persistent kernel, NEIGHBOR-flag sync instead of grid barrier.
//  - R9 post-mortem: grid barrier cost ~= kernel launch cost (neutral).
//    Dependencies are local: group g needs only the 8 torus neighbors'
//    group g-1 epilogues. Per-block monotonic done-counters + 8-neighbor
//    acquire polls replace the grid-wide sense barrier.
//  - WAR safety: neighbor's g+1 epilogue (which overwrites our g-input
//    parity buffers) requires our done>=g+1, i.e. we finished reading.
//  - Dead-write trim: non-final groups skip never-read interiors
//    (p/x inner 4x4, xb/q inner 2x2 of the 10x10 center); final group
//    writes ONLY x (all other state is dead).
//  - Fallback to proven R7 12-launch path if occupancy check fails.
#define XDIM 160
#define YDIM 160
#define TDIM 16
#define NB 2
#define T_ITERS 48
#define TILE 10
#define R1S 16            // level-1 region side (TILE+6)
#define R0S 18            // xbar staging side (TILE+8)
#define TPT (XDIM / TILE) // 16 tiles per side
#define NTHR 512
#define NGRP (T_ITERS / 4)
#define FLAG_STRIDE 16    // u32s between per-block flags (64B cachelines)

constexpr int VOL  = XDIM * YDIM * TDIM;  // 409600
constexpr int NX   = NB * VOL;            // 819200
constexpr int NBLK = NB * TPT * TPT;      // 512 blocks = exactly 2/CU

typedef _Float16 hreal;
typedef _Float16 half4 __attribute__((ext_vector_type(4)));

__device__ __forceinline__ float clampl(float v, float l) {
    return fminf(fmaxf(v, -l), l);
}
__device__ __forceinline__ int wrap(int v) {  // v in [-4, 164)
    return v < 0 ? v + XDIM : (v >= XDIM ? v - XDIM : v);
}
__device__ __forceinline__ int wrapT(int v) { // tile idx in [-1, TPT]
    return v < 0 ? v + TPT : (v >= TPT ? v - TPT : v);
}
__device__ __forceinline__ void ld4(const float* p, float* d) {
    float4 v = *(const float4*)p;
    d[0] = v.x; d[1] = v.y; d[2] = v.z; d[3] = v.w;
}
__device__ __forceinline__ void st4(float* p, const float* s) {
    *(float4*)p = make_float4(s[0], s[1], s[2], s[3]);
}
__device__ __forceinline__ void h2f4(const hreal* p, float* d) {
    half4 v = *(const half4*)p;
    d[0] = (float)v.x; d[1] = (float)v.y; d[2] = (float)v.z; d[3] = (float)v.w;
}
// DPP quad rotates (t is quad-uniform per line -> quads never diverge here).
__device__ __forceinline__ float qrot_up(float x) {  // lane i <- (i&~3)|((i+1)&3)
    return __int_as_float(__builtin_amdgcn_update_dpp(
        0, __float_as_int(x), 0x39, 0xF, 0xF, true));
}
__device__ __forceinline__ float qrot_dn(float x) {  // lane i <- (i&~3)|((i+3)&3)
    return __int_as_float(__builtin_amdgcn_update_dpp(
        0, __float_as_int(x), 0x93, 0xF, 0xF, true));
}

__global__ __launch_bounds__(256) void init_kernel(
    const float* __restrict__ x, const float* __restrict__ lam,
    float* __restrict__ pA, float* __restrict__ xA,
    hreal* __restrict__ xbAh, hreal* __restrict__ qAh,
    hreal* __restrict__ lamh, hreal* __restrict__ xnh,
    unsigned* __restrict__ flags)
{
    int i = blockIdx.x * blockDim.x + threadIdx.x;
    if (i < NX) {
        float v = x[i];
        pA[i] = v; xA[i] = v;
        xbAh[i] = (hreal)v;
        xnh[i]  = (hreal)v;
    }
    if (i < 3 * NX) {
        qAh[i]  = (hreal)0.f;
        lamh[i] = (hreal)lam[i];
    }
    if (flags && i < NBLK * FLAG_STRIDE) flags[i] = 0u;  // reset each replay
}

// ---------------------------------------------------------------------------
// R10 persistent kernel
// ---------------------------------------------------------------------------
__global__ __launch_bounds__(NTHR, 4) void pd_persist(
    const hreal* __restrict__ xnh, const hreal* __restrict__ lamh,
    float* __restrict__ pA, float* __restrict__ pB,
    float* __restrict__ xA, float* __restrict__ xB,
    hreal* __restrict__ xbA, hreal* __restrict__ xbB,
    hreal* __restrict__ qA, hreal* __restrict__ qB,
    unsigned* __restrict__ flags,
    float sigma, float inv1ps, float tau, float theta)
{
    __shared__ float xbS[R0S * R0S * TDIM];        // 20.25 KB
    __shared__ float q0S[(R1S + 1) * R1S * TDIM];  // 17 KB
    __shared__ float q1S[R1S * (R1S + 1) * TDIM];  // 17 KB  -> 54.25 KB

    const int tid = threadIdx.x;
    const int bid = blockIdx.x;
    const int b   = bid / (TPT * TPT);
    const int rem = bid % (TPT * TPT);
    const int tx  = rem / TPT, ty = rem % TPT;
    const int X0  = tx * TILE;
    const int Y0  = ty * TILE;
    const int xbase = b * VOL, qbase = b * 3 * VOL;
    const int t0 = (tid & 3) * 4;

    // my neighbor flag address (torus, same batch) for tid<8
    const unsigned* nbFlag = nullptr;
    if (tid < 8) {
        const int dxs[8] = {-1,-1,-1, 0, 0, 1, 1, 1};
        const int dys[8] = {-1, 0, 1,-1, 1,-1, 0, 1};
        int nx = wrapT(tx + dxs[tid]);
        int ny = wrapT(ty + dys[tid]);
        nbFlag = flags + (b * TPT * TPT + nx * TPT + ny) * FLAG_STRIDE;
    }

    // persistent per-slot state (2 slots/thread)
    float p[2][4], xv[2][4], xb[2][4], q0[2][4], q1[2][4], q2[2][4];
    half4 XNr[2], L0r[2], L1r[2], L2r[2];

    // constants: loaded exactly once for the whole 48 iterations
    #pragma unroll
    for (int m = 0; m < 2; ++m) {
        int line = 128 * m + (tid >> 2);
        int lx = line >> 4, ly = line & 15;
        int gx = wrap(X0 - 3 + lx), gy = wrap(Y0 - 3 + ly);
        int off  = xbase + (gx * YDIM + gy) * TDIM + t0;
        int qoff = qbase + (gx * YDIM + gy) * TDIM + t0;
        XNr[m] = *(const half4*)(xnh + off);
        L0r[m] = *(const half4*)(lamh + qoff);
        L1r[m] = *(const half4*)(lamh + qoff + VOL);
        L2r[m] = *(const half4*)(lamh + qoff + 2 * VOL);
    }
    half4 LRr;
    if (tid < 64) {
        int rly = tid >> 2;
        LRr = *(const half4*)(lamh + qbase +
              (wrap(X0 - 4) * YDIM + wrap(Y0 - 3 + rly)) * TDIM + t0);
    } else if (tid < 128) {
        int rlx = (tid - 64) >> 2;
        LRr = *(const half4*)(lamh + qbase + VOL +
              (wrap(X0 - 3 + rlx) * YDIM + wrap(Y0 - 4)) * TDIM + t0);
    }

    #pragma unroll 1
    for (int g = 0; g < NGRP; ++g) {
        const bool e = (g & 1) == 0;
        const bool first = (g == 0);
        const bool fin   = (g == NGRP - 1);
        const float* __restrict__ pIn  = e ? pA : pB;
        float* __restrict__ pOut       = e ? pB : pA;
        const float* __restrict__ xIn  = e ? xA : xB;
        float* __restrict__ xOut       = e ? xB : xA;
        const hreal* __restrict__ xbIn = e ? xbA : xbB;
        hreal* __restrict__ xbOut      = e ? xbB : xbA;
        const hreal* __restrict__ qIn  = e ? qA : qB;
        hreal* __restrict__ qOut       = e ? qB : qA;

        // ---- neighbor sync: need 8 neighbors' group g-1 epilogues ----
        if (!first) {
            if (tid < 8) {
                const unsigned tgt = (unsigned)g;
                for (unsigned it = 0; it < (1u << 22); ++it) {
                    if (__hip_atomic_load(nbFlag, __ATOMIC_ACQUIRE,
                                          __HIP_MEMORY_SCOPE_AGENT) >= tgt)
                        break;                       // watchdog: bail, not hang
                    __builtin_amdgcn_s_sleep(1);
                }
            }
            __syncthreads();
            __threadfence();   // acquire: drop stale cached ring lines
        }

        // ---- stage halos: full tile on g==0, ring-only afterwards ----
        for (int s = tid; s < R0S * R0S * 4; s += NTHR) {
            int sq = s & 3, ln = s >> 2;
            int rx = ln / R0S, ry = ln % R0S;
            if (!first && rx >= 4 && rx < 14 && ry >= 4 && ry < 14) continue;
            int gx = wrap(X0 - 4 + rx), gy = wrap(Y0 - 4 + ry);
            float v[4];
            h2f4(xbIn + xbase + (gx * YDIM + gy) * TDIM + sq * 4, v);
            st4(xbS + ln * TDIM + sq * 4, v);
        }
        for (int s = tid; s < 17 * 16 * 4; s += NTHR) {
            int sq = s & 3, ln = s >> 2;
            int sx = ln / 16, sy = ln % 16;
            if (!first && sx >= 3 && sx < 14 && sy >= 3 && sy < 13) continue;
            int gx = wrap(X0 - 4 + sx), gy = wrap(Y0 - 3 + sy);
            float v[4];
            h2f4(qIn + qbase + (gx * YDIM + gy) * TDIM + sq * 4, v);
            st4(q0S + ln * TDIM + sq * 4, v);
        }
        for (int s = tid; s < 16 * 17 * 4; s += NTHR) {
            int sq = s & 3, ln = s >> 2;
            int sx = ln / 17, sy = ln % 17;
            if (!first && sx >= 3 && sx < 13 && sy >= 3 && sy < 14) continue;
            int gx = wrap(X0 - 3 + sx), gy = wrap(Y0 - 4 + sy);
            float v[4];
            h2f4(qIn + qbase + VOL + (gx * YDIM + gy) * TDIM + sq * 4, v);
            st4(q1S + ln * TDIM + sq * 4, v);
        }

        // ---- per-slot reload: halo slots only (all slots on g==0) ----
        #pragma unroll
        for (int m = 0; m < 2; ++m) {
            int line = 128 * m + (tid >> 2);
            int lx = line >> 4, ly = line & 15;
            bool c = lx >= 3 && lx < 13 && ly >= 3 && ly < 13;
            if (first || !c) {
                int gx = wrap(X0 - 3 + lx), gy = wrap(Y0 - 3 + ly);
                int off  = xbase + (gx * YDIM + gy) * TDIM + t0;
                int qoff = qbase + (gx * YDIM + gy) * TDIM + t0;
                ld4(pIn + off, p[m]);
                ld4(xIn + off, xv[m]);
                h2f4(qIn + qoff + 2 * VOL, q2[m]);
            }
        }
        __syncthreads();
        #pragma unroll
        for (int m = 0; m < 2; ++m) {
            int line = 128 * m + (tid >> 2);
            int lx = line >> 4, ly = line & 15;
            bool c = lx >= 3 && lx < 13 && ly >= 3 && ly < 13;
            if (first || !c)
                ld4(xbS + ((lx + 1) * R0S + (ly + 1)) * TDIM + t0, xb[m]);
        }

        // ---- level loop: k = 1..4 ----
        #pragma unroll
        for (int k = 1; k <= 4; ++k) {
            const int lo = k - 1, hi = 17 - k;

            if (k == 1) {
                // level-1 backward rings (outside R1): q at lx=-1 / ly=-1
                if (tid < 64) {
                    int rly = tid >> 2;
                    float qr[4], xbc[4], xpx[4];
                    ld4(q0S + (0 * R1S + rly) * TDIM + t0, qr);
                    ld4(xbS + (0 * R0S + (rly + 1)) * TDIM + t0, xbc);
                    ld4(xbS + (1 * R0S + (rly + 1)) * TDIM + t0, xpx);
                    #pragma unroll
                    for (int j = 0; j < 4; ++j)
                        qr[j] = clampl(qr[j] + sigma * (xpx[j] - xbc[j]), (float)LRr[j]);
                    st4(q0S + (0 * R1S + rly) * TDIM + t0, qr);
                } else if (tid < 128) {
                    int rlx = (tid - 64) >> 2;
                    float qr[4], xbc[4], xpy[4];
                    ld4(q1S + (rlx * 17 + 0) * TDIM + t0, qr);
                    ld4(xbS + ((rlx + 1) * R0S + 0) * TDIM + t0, xbc);
                    ld4(xbS + ((rlx + 1) * R0S + 1) * TDIM + t0, xpy);
                    #pragma unroll
                    for (int j = 0; j < 4; ++j)
                        qr[j] = clampl(qr[j] + sigma * (xpy[j] - xbc[j]), (float)LRr[j]);
                    st4(q1S + (rlx * 17 + 0) * TDIM + t0, qr);
                }
            }

            // ===== phase B =====
            #pragma unroll
            for (int m = 0; m < 2; ++m) {
                int line = 128 * m + (tid >> 2);
                int lx = line >> 4, ly = line & 15;
                bool inX = (lx >= lo && lx < hi), inY = (ly >= lo && ly < hi);
                bool aq0 = inY && (lx >= lo - 1) && (lx < hi);
                bool aq1 = inX && (ly >= lo - 1) && (ly < hi);
                bool ax  = inX && inY;

                if (k == 1) {   // center slots keep last group's fp32 q0/q1
                    bool c = lx >= 3 && lx < 13 && ly >= 3 && ly < 13;
                    if (first || !c) {
                        ld4(q0S + ((lx + 1) * R1S + ly) * TDIM + t0, q0[m]);
                        ld4(q1S + (lx * 17 + (ly + 1)) * TDIM + t0, q1[m]);
                    }
                }
                if (aq0) {
                    float xpx[4];
                    ld4(xbS + ((lx + 2) * R0S + (ly + 1)) * TDIM + t0, xpx);
                    #pragma unroll
                    for (int j = 0; j < 4; ++j)
                        q0[m][j] = clampl(q0[m][j] + sigma * (xpx[j] - xb[m][j]),
                                          (float)L0r[m][j]);
                    st4(q0S + ((lx + 1) * R1S + ly) * TDIM + t0, q0[m]);
                }
                if (aq1) {
                    float xpy[4];
                    ld4(xbS + ((lx + 1) * R0S + (ly + 2)) * TDIM + t0, xpy);
                    #pragma unroll
                    for (int j = 0; j < 4; ++j)
                        q1[m][j] = clampl(q1[m][j] + sigma * (xpy[j] - xb[m][j]),
                                          (float)L1r[m][j]);
                    st4(q1S + (lx * 17 + (ly + 1)) * TDIM + t0, q1[m]);
                }
                if (ax) {
                    float xb_tp = qrot_up(xb[m][0]);   // xbar at t0+4
                    #pragma unroll
                    for (int j = 0; j < 4; ++j) {
                        float gt = ((j < 3) ? xb[m][j + 1] : xb_tp) - xb[m][j];
                        q2[m][j] = clampl(q2[m][j] + sigma * gt, (float)L2r[m][j]);
                        p[m][j]  = (p[m][j] + sigma * (xb[m][j] - (float)XNr[m][j]))
                                   * inv1ps;
                    }
                }
            }
            __syncthreads();

            // ===== phase C =====
            #pragma unroll
            for (int m = 0; m < 2; ++m) {
                int line = 128 * m + (tid >> 2);
                int lx = line >> 4, ly = line & 15;
                bool ax = (lx >= lo && lx < hi && ly >= lo && ly < hi);
                if (ax) {
                    float q0b[4], q1b[4];
                    ld4(q0S + (lx * R1S + ly) * TDIM + t0, q0b);
                    ld4(q1S + (lx * 17 + ly) * TDIM + t0, q1b);
                    float q2tm = qrot_dn(q2[m][3]);          // new, t0-1
                    #pragma unroll
                    for (int j = 0; j < 4; ++j) {
                        float q2p = (j == 0) ? q2tm : q2[m][j - 1];
                        float div = (q0b[j] - q0[m][j]) + (q1b[j] - q1[m][j])
                                  + (q2p - q2[m][j]);
                        float xnew = xv[m][j] - tau * (p[m][j] + div);
                        xb[m][j] = xnew + theta * (xnew - xv[m][j]);
                        xv[m][j] = xnew;
                    }
                    // k=4 also stores: keeps LDS center valid across groups
                    st4(xbS + ((lx + 1) * R0S + (ly + 1)) * TDIM + t0, xb[m]);
                }
            }
            if (k < 4) __syncthreads();
        }

        // ---- epilogue: only what someone will actually read ----
        // read-sets: p/x -> neighbor halo-slot reload (owner offsets 0..2,7..9);
        //            xb/q -> rings+halo (owner offsets 0..3,6..9);
        //            final group: only x is live (full center to d_out).
        #pragma unroll
        for (int m = 0; m < 2; ++m) {
            int line = 128 * m + (tid >> 2);
            int lx = line >> 4, ly = line & 15;
            if (lx >= 3 && lx < 13 && ly >= 3 && ly < 13) {
                int ox = lx - 3, oy = ly - 3;      // tile offsets 0..9
                int gx = X0 + ox, gy = Y0 + oy;
                int off  = xbase + (gx * YDIM + gy) * TDIM + t0;
                int qoff = qbase + (gx * YDIM + gy) * TDIM + t0;
                if (fin) {
                    st4(xOut + off, xv[m]);        // d_out
                } else {
                    bool px_skip = (ox >= 3 && ox < 7 && oy >= 3 && oy < 7);
                    bool q_skip  = (ox >= 4 && ox < 6 && oy >= 4 && oy < 6);
                    if (!px_skip) {
                        st4(pOut + off, p[m]);
                        st4(xOut + off, xv[m]);
                    }
                    if (!q_skip) {
                        half4 h;
                        h.x = (hreal)xb[m][0]; h.y = (hreal)xb[m][1];
                        h.z = (hreal)xb[m][2]; h.w = (hreal)xb[m][3];
                        *(half4*)(xbOut + off) = h;
                        h.x = (hreal)q0[m][0]; h.y = (hreal)q0[m][1];
                        h.z = (hreal)q0[m][2]; h.w = (hreal)q0[m][3];
                        *(half4*)(qOut + qoff) = h;
                        h.x = (hreal)q1[m][0]; h.y = (hreal)q1[m][1];
                        h.z = (hreal)q1[m][2]; h.w = (hreal)q1[m][3];
                        *(half4*)(qOut + qoff + VOL) = h;
                        h.x = (hreal)q2[m][0]; h.y = (hreal)q2[m][1];
                        h.z = (hreal)q2[m][2]; h.w = (hreal)q2[m][3];
                        *(half4*)(qOut + qoff + 2 * VOL) = h;
                    }
                }
            }
        }

        // ---- publish: done-count = g+1 ----
        if (!fin) {
            __threadfence();       // release my stores (agent scope)
            __syncthreads();       // all threads' stores drained + fenced
            if (tid == 0)
                __hip_atomic_store(flags + bid * FLAG_STRIDE, (unsigned)(g + 1),
                                   __ATOMIC_RELEASE, __HIP_MEMORY_SCOPE_AGENT);
        }
    }
}

// ---------------------------------------------------------------------------
// Fallback: proven R7 12-launch kernel, unchanged
// ---------------------------------------------------------------------------
__global__ __launch_bounds__(NTHR, 4) void pd_step4(
    const hreal* __restrict__ xnh, const hreal* __restrict__ lamh,
    const float* __restrict__ pIn, float* __restrict__ pOut,
    const float* __restrict__ xIn, float* __restrict__ xOut,
    const hreal* __restrict__ xbIn, hreal* __restrict__ xbOut,
    const hreal* __restrict__ qIn, hreal* __restrict__ qOut,
    float sigma, float inv1ps, float tau, float theta)
{
    __shared__ float xbS[R0S * R0S * TDIM];
    __shared__ float q0S[(R1S + 1) * R1S * TDIM];
    __shared__ float q1S[R1S * (R1S + 1) * TDIM];

    const int tid = threadIdx.x;
    const int b   = blockIdx.x / (TPT * TPT);
    const int rem = blockIdx.x % (TPT * TPT);
    const int X0  = (rem / TPT) * TILE;
    const int Y0  = (rem % TPT) * TILE;
    const int xbase = b * VOL, qbase = b * 3 * VOL;

    const int qd = tid & 3, t0 = qd * 4;
    const int lane  = tid & 63;
    const int upSrc = (lane & 60) | ((lane + 1) & 3);
    const int dnSrc = (lane & 60) | ((lane + 3) & 3);

    for (int s = tid; s < R0S * R0S * 4; s += NTHR) {
        int sq = s & 3, ln = s >> 2;
        int rx = ln / R0S, ry = ln % R0S;
        int gx = wrap(X0 - 4 + rx), gy = wrap(Y0 - 4 + ry);
        float v[4];
        h2f4(xbIn + xbase + (gx * YDIM + gy) * TDIM + sq * 4, v);
        st4(xbS + ln * TDIM + sq * 4, v);
    }
    for (int s = tid; s < 17 * 16 * 4; s += NTHR) {
        int sq = s & 3, ln = s >> 2;
        int sx = ln / 16, sy = ln % 16;
        int gx = wrap(X0 - 4 + sx), gy = wrap(Y0 - 3 + sy);
        float v[4];
        h2f4(qIn + qbase + (gx * YDIM + gy) * TDIM + sq * 4, v);
        st4(q0S + ln * TDIM + sq * 4, v);
    }
    for (int s = tid; s < 16 * 17 * 4; s += NTHR) {
        int sq = s & 3, ln = s >> 2;
        int sx = ln / 17, sy = ln % 17;
        int gx = wrap(X0 - 3 + sx), gy = wrap(Y0 - 4 + sy);
        float v[4];
        h2f4(qIn + qbase + VOL + (gx * YDIM + gy) * TDIM + sq * 4, v);
        st4(q1S + ln * TDIM + sq * 4, v);
    }

    float p[2][4], xv[2][4], xb[2][4], q0[2][4], q1[2][4], q2[2][4];
    half4 XNr[2], L0r[2], L1r[2], L2r[2];
    #pragma unroll
    for (int m = 0; m < 2; ++m) {
        int line = 128 * m + (tid >> 2);
        int lx = line >> 4, ly = line & 15;
        int gx = wrap(X0 - 3 + lx), gy = wrap(Y0 - 3 + ly);
        int off  = xbase + (gx * YDIM + gy) * TDIM + t0;
        int qoff = qbase + (gx * YDIM + gy) * TDIM + t0;
        ld4(pIn + off, p[m]);
        ld4(xIn + off, xv[m]);
        h2f4(qIn + qoff + 2 * VOL, q2[m]);
        XNr[m] = *(const half4*)(xnh + off);
        L0r[m] = *(const half4*)(lamh + qoff);
        L1r[m] = *(const half4*)(lamh + qoff + VOL);
        L2r[m] = *(const half4*)(lamh + qoff + 2 * VOL);
    }

    half4 LRr;
    if (tid < 64) {
        int rly = tid >> 2;
        LRr = *(const half4*)(lamh + qbase +
              (wrap(X0 - 4) * YDIM + wrap(Y0 - 3 + rly)) * TDIM + t0);
    } else if (tid < 128) {
        int rlx = (tid - 64) >> 2;
        LRr = *(const half4*)(lamh + qbase + VOL +
              (wrap(X0 - 3 + rlx) * YDIM + wrap(Y0 - 4)) * TDIM + t0);
    }

    __syncthreads();

    #pragma unroll
    for (int m = 0; m < 2; ++m) {
        int line = 128 * m + (tid >> 2);
        int lx = line >> 4, ly = line & 15;
        ld4(xbS + ((lx + 1) * R0S + (ly + 1)) * TDIM + t0, xb[m]);
    }

    #pragma unroll
    for (int k = 1; k <= 4; ++k) {
        const int lo = k - 1, hi = 17 - k;

        if (k == 1) {
            if (tid < 64) {
                int rly = tid >> 2;
                float qr[4], xbc[4], xpx[4];
                ld4(q0S + (0 * R1S + rly) * TDIM + t0, qr);
                ld4(xbS + (0 * R0S + (rly + 1)) * TDIM + t0, xbc);
                ld4(xbS + (1 * R0S + (rly + 1)) * TDIM + t0, xpx);
                #pragma unroll
                for (int j = 0; j < 4; ++j)
                    qr[j] = clampl(qr[j] + sigma * (xpx[j] - xbc[j]), (float)LRr[j]);
                st4(q0S + (0 * R1S + rly) * TDIM + t0, qr);
            } else if (tid < 128) {
                int rlx = (tid - 64) >> 2;
                float qr[4], xbc[4], xpy[4];
                ld4(q1S + (rlx * 17 + 0) * TDIM + t0, qr);
                ld4(xbS + ((rlx + 1) * R0S + 0) * TDIM + t0, xbc);
                ld4(xbS + ((rlx + 1) * R0S + 1) * TDIM + t0, xpy);
                #pragma unroll
                for (int j = 0; j < 4; ++j)
                    qr[j] = clampl(qr[j] + sigma * (xpy[j] - xbc[j]), (float)LRr[j]);
                st4(q1S + (rlx * 17 + 0) * TDIM + t0, qr);
            }
        }

        #pragma unroll
        for (int m = 0; m < 2; ++m) {
            int line = 128 * m + (tid >> 2);
            int lx = line >> 4, ly = line & 15;
            bool inX = (lx >= lo && lx < hi), inY = (ly >= lo && ly < hi);
            bool aq0 = inY && (lx >= lo - 1) && (lx < hi);
            bool aq1 = inX && (ly >= lo - 1) && (ly < hi);
            bool ax  = inX && inY;

            if (k == 1) {
                ld4(q0S + ((lx + 1) * R1S + ly) * TDIM + t0, q0[m]);
                ld4(q1S + (lx * 17 + (ly + 1)) * TDIM + t0, q1[m]);
            }
            if (aq0) {
                float xpx[4];
                ld4(xbS + ((lx + 2) * R0S + (ly + 1)) * TDIM + t0, xpx);
                #pragma unroll
                for (int j = 0; j < 4; ++j)
                    q0[m][j] = clampl(q0[m][j] + sigma * (xpx[j] - xb[m][j]),
                                      (float)L0r[m][j]);
                st4(q0S + ((lx + 1) * R1S + ly) * TDIM + t0, q0[m]);
            }
            if (aq1) {
                float xpy[4];
                ld4(xbS + ((lx + 1) * R0S + (ly + 2)) * TDIM + t0, xpy);
                #pragma unroll
                for (int j = 0; j < 4; ++j)
                    q1[m][j] = clampl(q1[m][j] + sigma * (xpy[j] - xb[m][j]),
                                      (float)L1r[m][j]);
                st4(q1S + (lx * 17 + (ly + 1)) * TDIM + t0, q1[m]);
            }
            if (ax) {
                float xb_tp = __shfl(xb[m][0], upSrc, 64);
                #pragma unroll
                for (int j = 0; j < 4; ++j) {
                    float gt = ((j < 3) ? xb[m][j + 1] : xb_tp) - xb[m][j];
                    q2[m][j] = clampl(q2[m][j] + sigma * gt, (float)L2r[m][j]);
                    p[m][j]  = (p[m][j] + sigma * (xb[m][j] - (float)XNr[m][j]))
                               * inv1ps;
                }
            }
        }
        __syncthreads();

        #pragma unroll
        for (int m = 0; m < 2; ++m) {
            int line = 128 * m + (tid >> 2);
            int lx = line >> 4, ly = line & 15;
            bool ax = (lx >= lo && lx < hi && ly >= lo && ly < hi);
            if (ax) {
                float q0b[4], q1b[4];
                ld4(q0S + (lx * R1S + ly) * TDIM + t0, q0b);
                ld4(q1S + (lx * 17 + ly) * TDIM + t0, q1b);
                float q2tm = __shfl(q2[m][3], dnSrc, 64);
                #pragma unroll
                for (int j = 0; j < 4; ++j) {
                    float q2p = (j == 0) ? q2tm : q2[m][j - 1];
                    float div = (q0b[j] - q0[m][j]) + (q1b[j] - q1[m][j])
                              + (q2p - q2[m][j]);
                    float xnew = xv[m][j] - tau * (p[m][j] + div);
                    xb[m][j] = xnew + theta * (xnew - xv[m][j]);
                    xv[m][j] = xnew;
                }
                if (k < 4)
                    st4(xbS + ((lx + 1) * R0S + (ly + 1)) * TDIM + t0, xb[m]);
            }
        }
        if (k < 4) __syncthreads();
    }

    #pragma unroll
    for (int m = 0; m < 2; ++m) {
        int line = 128 * m + (tid >> 2);
        int lx = line >> 4, ly = line & 15;
        if (lx >= 3 && lx < 13 && ly >= 3 && ly < 13) {
            int gx = X0 + lx - 3, gy = Y0 + ly - 3;
            int off  = xbase + (gx * YDIM + gy) * TDIM + t0;
            int qoff = qbase + (gx * YDIM + gy) * TDIM + t0;
            st4(pOut + off, p[m]);
            st4(xOut + off, xv[m]);
            half4 h;
            h.x = (hreal)xb[m][0]; h.y = (hreal)xb[m][1];
            h.z = (hreal)xb[m][2]; h.w = (hreal)xb[m][3];
            *(half4*)(xbOut + off) = h;
            h.x = (hreal)q0[m][0]; h.y = (hreal)q0[m][1];
            h.z = (hreal)q0[m][2]; h.w = (hreal)q0[m][3];
            *(half4*)(qOut + qoff) = h;
            h.x = (hreal)q1[m][0]; h.y = (hreal)q1[m][1];
            h.z = (hreal)q1[m][2]; h.w = (hreal)q1[m][3];
            *(half4*)(qOut + qoff + VOL) = h;
            h.x = (hreal)q2[m][0]; h.y = (hreal)q2[m][1];
            h.z = (hreal)q2[m][2]; h.w = (hreal)q2[m][3];
            *(half4*)(qOut + qoff + 2 * VOL) = h;
        }
    }
}

extern "C" void kernel_launch(void* const* d_in, const int* in_sizes, int n_in,
                              void* d_out, int out_size, void* d_ws, size_t ws_size,
                              hipStream_t stream) {
    const float* x   = (const float*)d_in[0];
    const float* lam = (const float*)d_in[1];
    float* out = (float*)d_out;
    float* ws  = (float*)d_ws;

    float* pA  = ws;
    float* pB  = ws + (size_t)NX;
    float* xBb = ws + (size_t)2 * NX;
    float* xAb = out;   // final group (odd parity) writes A family -> d_out
    hreal* hb  = (hreal*)(ws + (size_t)3 * NX);
    hreal* xbAh = hb;
    hreal* xbBh = hb + (size_t)NX;
    hreal* qAh  = hb + (size_t)2 * NX;
    hreal* qBh  = hb + (size_t)5 * NX;
    hreal* lamh = hb + (size_t)8 * NX;
    hreal* xnh  = hb + (size_t)11 * NX;
    unsigned* flags = (unsigned*)(ws + (size_t)9 * NX);  // 512*16 u32 = 32 KB

    const size_t ws_need = (size_t)9 * NX * sizeof(float)
                         + (size_t)NBLK * FLAG_STRIDE * sizeof(unsigned);

    const double s10 = 1.0 / (1.0 + exp(-10.0));
    const double L   = sqrt(13.0);
    float sigma  = (float)(s10 / L);
    float tau    = sigma;
    float theta  = (float)s10;
    float inv1ps = (float)(1.0 / (1.0 + s10 / L));

    // Persistent path needs all 512 blocks co-resident (2 blocks/CU x 256 CU).
    static int persist_ok = -1;
    if (persist_ok < 0) {
        int nb = 0;
        hipError_t oe = hipOccupancyMaxActiveBlocksPerMultiprocessor(
            &nb, pd_persist, NTHR, 0);
        persist_ok = (oe == hipSuccess && nb >= 2) ? 1 : 0;
        (void)hipGetLastError();
    }
    const bool use_persist = persist_ok == 1 && ws_size >= ws_need;

    init_kernel<<<(3 * NX + 255) / 256, 256, 0, stream>>>(
        x, lam, pA, xAb, xbAh, qAh, lamh, xnh, use_persist ? flags : nullptr);

    if (use_persist) {
        pd_persist<<<NBLK, NTHR, 0, stream>>>(
            xnh, lamh, pA, pB, xAb, xBb, xbAh, xbBh, qAh, qBh, flags,
            sigma, inv1ps, tau, theta);
    } else {
        for (int j = 0; j < NGRP; ++j) {
            const bool e = (j & 1) == 0;
            pd_step4<<<NBLK, NTHR, 0, stream>>>(
                xnh, lamh,
                e ? pA : pB,   e ? pB : pA,
                e ? xAb : xBb, e ? xBb : xAb,
                e ? xbAh : xbBh, e ? xbBh : xbAh,
                e ? qAh : qBh,  e ? qBh : qAh,
                sigma, inv1ps, tau, theta);
        }
    }
}